// Round 1
// baseline (263.103 us; speedup 1.0000x reference)
//
#include <hip/hip_runtime.h>
#include <math.h>

constexpr int KK = 2;
constexpr int HH = 4;
constexpr int NN = 4096;
constexpr int DD = 64;
constexpr int OO = 64;
constexpr int NU = 4000;
constexpr int CC = 2;
constexpr float LOG2E = 1.44269504088896340736f;

__device__ __forceinline__ float fexp2(float x) {
#if __has_builtin(__builtin_amdgcn_exp2f)
  return __builtin_amdgcn_exp2f(x);
#else
  return exp2f(x);
#endif
}
__device__ __forceinline__ float frcp(float x) {
#if __has_builtin(__builtin_amdgcn_rcpf)
  return __builtin_amdgcn_rcpf(x);
#else
  return 1.0f / x;
#endif
}
// tanh(x) = 1 - 2/(exp(2x)+1), exp via v_exp_f32. Saturates correctly at +-inf.
__device__ __forceinline__ float ftanh(float x) {
  float e = fexp2(x * (2.0f * LOG2E));
  return 1.0f - 2.0f * frcp(e + 1.0f);
}

// Phase 1: per (k,h) compute h_prime rows, then scalars:
//   src'[i] = (tanh(hp_i) . a_src) * log2e
//   dst'[j] = (tanh(hp_j) . a_dst) * log2e
//   g_c[j]  = hp_j . fc_w[c, k*O : k*O+O]
// att[kh][j] = {dst', g0, g1, 0}
// grid: (N/128, K*H), block 128. Each thread: 4 rows x 16 o-slice.
__global__ __launch_bounds__(128) void gat_phase1(
    const float* __restrict__ hsrc, const float* __restrict__ w,
    const float* __restrict__ a_src, const float* __restrict__ a_dst,
    const float* __restrict__ fc_w,
    float* __restrict__ src_s, float4* __restrict__ att) {
  const int kh = blockIdx.y;       // 0..7
  const int k = kh >> 2;           // HH=4
  const int i0 = blockIdx.x * 128;
  const int tid = threadIdx.x;

  __shared__ float w_s[DD * OO];        // [f][o]
  __shared__ float h_s[DD][128];        // transposed [f][local row]
  __shared__ float asrc_s[OO], adst_s[OO], fw0[OO], fw1[OO];
  __shared__ float redl[4][32][17];     // [o-group][row-group][r*4+v], padded

  const float* wp = w + (size_t)kh * DD * OO;
  for (int t = tid; t < DD * OO; t += 128) w_s[t] = wp[t];
  if (tid < OO) {
    asrc_s[tid] = a_src[kh * OO + tid];
    adst_s[tid] = a_dst[kh * OO + tid];
    fw0[tid] = fc_w[0 * (KK * OO) + k * OO + tid];
    fw1[tid] = fc_w[1 * (KK * OO) + k * OO + tid];
  }
  {
    const float* hr = hsrc + (size_t)(i0 + tid) * DD;
#pragma unroll
    for (int f4 = 0; f4 < DD; f4 += 4) {
      float4 v = *(const float4*)(hr + f4);
      h_s[f4 + 0][tid] = v.x;
      h_s[f4 + 1][tid] = v.y;
      h_s[f4 + 2][tid] = v.z;
      h_s[f4 + 3][tid] = v.w;
    }
  }
  __syncthreads();

  const int og = tid >> 5;   // 0..3  -> o0
  const int rg = tid & 31;   // 0..31 -> r0
  const int o0 = og * 16;
  const int r0 = rg * 4;

  float hp[4][16];
#pragma unroll
  for (int r = 0; r < 4; ++r)
#pragma unroll
    for (int o = 0; o < 16; ++o) hp[r][o] = 0.0f;

#pragma unroll 4
  for (int f = 0; f < DD; ++f) {
    float hr0 = h_s[f][r0 + 0];
    float hr1 = h_s[f][r0 + 1];
    float hr2 = h_s[f][r0 + 2];
    float hr3 = h_s[f][r0 + 3];
#pragma unroll
    for (int o = 0; o < 16; ++o) {
      float wv = w_s[f * OO + o0 + o];
      hp[0][o] = fmaf(hr0, wv, hp[0][o]);
      hp[1][o] = fmaf(hr1, wv, hp[1][o]);
      hp[2][o] = fmaf(hr2, wv, hp[2][o]);
      hp[3][o] = fmaf(hr3, wv, hp[3][o]);
    }
  }

#pragma unroll
  for (int r = 0; r < 4; ++r) {
    float sp = 0.0f, dp = 0.0f, g0 = 0.0f, g1 = 0.0f;
#pragma unroll
    for (int o = 0; o < 16; ++o) {
      float v = hp[r][o];
      float t = ftanh(v);
      sp = fmaf(t, asrc_s[o0 + o], sp);
      dp = fmaf(t, adst_s[o0 + o], dp);
      g0 = fmaf(v, fw0[o0 + o], g0);
      g1 = fmaf(v, fw1[o0 + o], g1);
    }
    redl[og][rg][r * 4 + 0] = sp;
    redl[og][rg][r * 4 + 1] = dp;
    redl[og][rg][r * 4 + 2] = g0;
    redl[og][rg][r * 4 + 3] = g1;
  }
  __syncthreads();

  {  // one thread per local row: combine the 4 o-groups, write out
    const int lr = tid;
    const int rrg = lr >> 2, rr = lr & 3;
    float sp = 0.0f, dp = 0.0f, g0 = 0.0f, g1 = 0.0f;
#pragma unroll
    for (int q = 0; q < 4; ++q) {
      sp += redl[q][rrg][rr * 4 + 0];
      dp += redl[q][rrg][rr * 4 + 1];
      g0 += redl[q][rrg][rr * 4 + 2];
      g1 += redl[q][rrg][rr * 4 + 3];
    }
    const int i = i0 + lr;
    src_s[kh * NN + i] = sp * LOG2E;
    att[(size_t)kh * NN + i] = make_float4(dp * LOG2E, g0, g1, 0.0f);
  }
}

// Phase 2: for each (k, row-block of 8): scan all j, accumulate
//   p = adj * exp2(leaky(src'+dst')); l += p; acc_c += p*g_c
// lanes split j (float4 adj loads); butterfly + LDS reduce; write S[k][i][c].
__global__ __launch_bounds__(128) void gat_phase2(
    const float* __restrict__ adj, const float* __restrict__ src_s,
    const float4* __restrict__ att, float* __restrict__ S) {
  const int k = blockIdx.y;
  const int i0 = blockIdx.x * 8;
  const int tid = threadIdx.x;
  const int lane = tid & 63;
  const int wv = tid >> 6;

  float srcv[8][4];  // uniform -> scalar loads
#pragma unroll
  for (int r = 0; r < 8; ++r)
#pragma unroll
    for (int q = 0; q < 4; ++q)
      srcv[r][q] = src_s[(k * HH + q) * NN + i0 + r];

  float lacc[8][4];
  float cacc[8][4][2];
#pragma unroll
  for (int r = 0; r < 8; ++r)
#pragma unroll
    for (int q = 0; q < 4; ++q) {
      lacc[r][q] = 0.0f;
      cacc[r][q][0] = 0.0f;
      cacc[r][q][1] = 0.0f;
    }

  const float* adjk = adj + (size_t)k * NN * NN;
  const float4* attk = att + (size_t)k * HH * NN;

  for (int jb = tid * 4; jb < NN; jb += 512) {
    float4 aj[8];
#pragma unroll
    for (int r = 0; r < 8; ++r)
      aj[r] = *(const float4*)(adjk + (size_t)(i0 + r) * NN + jb);
#pragma unroll
    for (int jj = 0; jj < 4; ++jj) {
      float4 av[4];
      av[0] = attk[0 * NN + jb + jj];
      av[1] = attk[1 * NN + jb + jj];
      av[2] = attk[2 * NN + jb + jj];
      av[3] = attk[3 * NN + jb + jj];
#pragma unroll
      for (int r = 0; r < 8; ++r) {
        const float a = (jj == 0) ? aj[r].x
                      : (jj == 1) ? aj[r].y
                      : (jj == 2) ? aj[r].z
                                  : aj[r].w;
#pragma unroll
        for (int q = 0; q < 4; ++q) {
          float s = srcv[r][q] + av[q].x;
          float sl = fmaxf(s, 0.2f * s);   // leaky, already in log2 units
          float p = a * fexp2(sl);
          lacc[r][q] += p;
          cacc[r][q][0] = fmaf(p, av[q].y, cacc[r][q][0]);
          cacc[r][q][1] = fmaf(p, av[q].z, cacc[r][q][1]);
        }
      }
    }
  }

  // butterfly reduce across 64 lanes (all 96 accumulators)
#pragma unroll
  for (int r = 0; r < 8; ++r)
#pragma unroll
    for (int q = 0; q < 4; ++q) {
      float x0 = lacc[r][q], x1 = cacc[r][q][0], x2 = cacc[r][q][1];
#pragma unroll
      for (int off = 32; off > 0; off >>= 1) {
        x0 += __shfl_xor(x0, off, 64);
        x1 += __shfl_xor(x1, off, 64);
        x2 += __shfl_xor(x2, off, 64);
      }
      lacc[r][q] = x0;
      cacc[r][q][0] = x1;
      cacc[r][q][1] = x2;
    }

  __shared__ float red2[2][96];
  if (lane == 0) {
#pragma unroll
    for (int r = 0; r < 8; ++r)
#pragma unroll
      for (int q = 0; q < 4; ++q) {
        red2[wv][(r * 4 + q) * 3 + 0] = lacc[r][q];
        red2[wv][(r * 4 + q) * 3 + 1] = cacc[r][q][0];
        red2[wv][(r * 4 + q) * 3 + 2] = cacc[r][q][1];
      }
  }
  __syncthreads();
  if (tid < 16) {
    const int r = tid >> 1, c = tid & 1;
    float sum = 0.0f;
#pragma unroll
    for (int q = 0; q < 4; ++q) {
      float lsum = red2[0][(r * 4 + q) * 3 + 0] + red2[1][(r * 4 + q) * 3 + 0];
      float asum = red2[0][(r * 4 + q) * 3 + 1 + c] + red2[1][(r * 4 + q) * 3 + 1 + c];
      sum += asum / lsum;
    }
    S[((size_t)k * NU + i0 + r) * CC + c] = 0.25f * sum;  // mean over heads
  }
}

// Phase 3: combine the two kinds, add bias, log_softmax over C=2.
__global__ __launch_bounds__(256) void gat_phase3(
    const float* __restrict__ S, const float* __restrict__ fc_b,
    float* __restrict__ out) {
  const int i = blockIdx.x * 256 + threadIdx.x;
  if (i >= NU) return;
  float l0 = S[(size_t)(0 * NU + i) * CC + 0] + S[((size_t)NU + i) * CC + 0] + fc_b[0];
  float l1 = S[(size_t)(0 * NU + i) * CC + 1] + S[((size_t)NU + i) * CC + 1] + fc_b[1];
  float m = fmaxf(l0, l1);
  float lse = m + logf(expf(l0 - m) + expf(l1 - m));
  out[i * CC + 0] = l0 - lse;
  out[i * CC + 1] = l1 - lse;
}

extern "C" void kernel_launch(void* const* d_in, const int* in_sizes, int n_in,
                              void* d_out, int out_size, void* d_ws, size_t ws_size,
                              hipStream_t stream) {
  const float* hsrc  = (const float*)d_in[0];  // (1,4096,64)
  const float* hadj  = (const float*)d_in[1];  // (2,1,4096,4096)
  const float* w     = (const float*)d_in[2];  // (2,4,64,64)
  const float* a_src = (const float*)d_in[3];  // (2,4,64,1)
  const float* a_dst = (const float*)d_in[4];  // (2,4,64,1)
  const float* fc_w  = (const float*)d_in[5];  // (2,128)
  const float* fc_b  = (const float*)d_in[6];  // (2,)
  float* out = (float*)d_out;                  // (1,4000,2) fp32

  char* ws = (char*)d_ws;
  float*  src_s = (float*)ws;                       // K*H*N floats   (128 KB)
  float4* att   = (float4*)(ws + 131072);           // K*H*N float4   (512 KB)
  float*  S     = (float*)(ws + 131072 + 524288);   // K*NU*C floats  (64 KB)

  dim3 g1(NN / 128, KK * HH);
  gat_phase1<<<g1, 128, 0, stream>>>(hsrc, w, a_src, a_dst, fc_w, src_s, att);
  dim3 g2(NU / 8, KK);
  gat_phase2<<<g2, 128, 0, stream>>>(hadj, src_s, att, S);
  gat_phase3<<<(NU + 255) / 256, 256, 0, stream>>>(S, fc_b, out);
}